// Round 4
// baseline (339.999 us; speedup 1.0000x reference)
//
#include <hip/hip_runtime.h>
#include <hip/hip_bf16.h>

typedef _Float16 half8 __attribute__((ext_vector_type(8)));
typedef _Float16 half4v __attribute__((ext_vector_type(4)));
typedef float floatx4 __attribute__((ext_vector_type(4)));
typedef float floatx16 __attribute__((ext_vector_type(16)));

// ---------------------------------------------------------------------------
// R20: geometry = R18/R19 (128x64 wave tile, 4m x 2n, BM=128, 4-wave blocks,
// 2 blocks/CU = 2 waves/SIMD). New: A-REGISTER PING-PONG, 1 kstep ahead.
//
// Theory: R16/R18/R19 all measure 264-276 us @ MfmaUtil 44% with identical
// per-CU pipe totals (matrix 512 cy/kstep, LDS-A 384, epilogue ~150). Layer
// time ~= matrix + LDS exactly -> pipes serialized. Cause: every wave reads
// A(k) right before MFMA(k); barrier-aligned waves phase-lock (all read ->
// LDS saturated/matrix idle; all MFMA -> LDS idle). Fix: double-buffer A in
// registers: issue ds_reads for group g+1, sched_barrier(0) pin, then MFMA
// group g from RESIDENT regs (prefetch distance = 8 MFMA ~ 256-512 cy >>
// LDS latency). W keeps the proven 4-slot ring (~4 ksteps ahead, vmem).
//
// Act layout: chunk-major, 128-row chunks:
//   off(row, col) = (col>>3)*1024 + row*8 + (col&7)   [halfs]
// LDS: act 128x256 fp16 (64 KiB, in-place) + x 128x48 (12 KiB) = 76 KiB.
// __launch_bounds__(256,2) -> 256-reg cap (acc 128 + A-ring 32 + W 32 + ~40).
// ---------------------------------------------------------------------------
__device__ __forceinline__ int cmaj(int row, int col) {
    return ((col >> 3) << 10) + (row << 3) + (col & 7);
}

// ---------------------------------------------------------------------------
// Weight pre-pack (unchanged, proven R5-R19): fp32 (K,N) row-major -> fp16
// fragment order; lane L holds W[kt*16 + 8*(L>>5) + j][nt*32 + (L&31)].
// Fed to the MFMA *A* operand so D = C^T. K zero-padded: L1 39->64 (KT=4),
// L5 295->320 (KT=20), others 256 (KT=16). L9 N 4->32. Tile starts (1KB):
// {0,32,160,288,416,576,704,832,960}, total 976 tiles = 999424 B in d_ws.
// ---------------------------------------------------------------------------
__global__ void pack_w32(const float* __restrict__ w1, const float* __restrict__ w2,
                         const float* __restrict__ w3, const float* __restrict__ w4,
                         const float* __restrict__ w5, const float* __restrict__ w6,
                         const float* __restrict__ w7, const float* __restrict__ w8,
                         const float* __restrict__ w9, _Float16* __restrict__ dst) {
    const int tileStart[10] = {0, 32, 160, 288, 416, 576, 704, 832, 960, 976};
    const int Ks[9] = {39, 256, 256, 256, 295, 256, 256, 256, 256};
    const int Ns[9] = {256, 256, 256, 256, 256, 256, 256, 256, 4};
    const int Tn[9] = {8, 8, 8, 8, 8, 8, 8, 8, 1};
    const float* ws[9] = {w1, w2, w3, w4, w5, w6, w7, w8, w9};

    int g = blockIdx.x * blockDim.x + threadIdx.x;
    int tile = g >> 6, lane = g & 63;
    if (tile >= 976) return;
    int layer = 0;
    while (tile >= tileStart[layer + 1]) layer++;
    int t = tile - tileStart[layer];
    int tn = Tn[layer];
    int kt = t / tn, nt = t - kt * tn;
    int k0 = kt * 16 + (lane >> 5) * 8;
    int n = nt * 32 + (lane & 31);
    const float* w = ws[layer];
    int K = Ks[layer], N = Ns[layer];
    _Float16 v[8];
#pragma unroll
    for (int j = 0; j < 8; j++) {
        int k = k0 + j;
        v[j] = (k < K && n < N) ? (_Float16)w[k * N + n] : (_Float16)0.f;
    }
    *(half8*)(dst + (size_t)tile * 512 + lane * 8) = *(half8*)v;
}

// Prefetch one kstep's 4 A-frags into a register buffer.
// AMODE 0: act. 1: runtime route (s >= KS0 -> x; only L5 pays the select).
// 2: entirely x.
template <int AMODE, int KS0>
__device__ __forceinline__ void prefA(half8 (&A)[4], const _Float16* aB,
                                      const _Float16* xB, int s) {
    const _Float16* p;
    if constexpr (AMODE == 2) {
        p = xB + s * 2048;
    } else if constexpr (AMODE == 1) {
        p = (s >= KS0) ? (xB + (s - KS0) * 2048) : (aB + s * 2048);
    } else {
        p = aB + s * 2048;
    }
#pragma unroll
    for (int mi = 0; mi < 4; mi++) A[mi] = *(const half8*)(p + mi * 256);
}

// 8 MFMAs (4m x 2n) from fully-resident registers.
__device__ __forceinline__ void mfma8(const half8 (&A)[4], half8 wa, half8 wb,
                                      floatx16 (&acc)[4][2]) {
    __builtin_amdgcn_s_setprio(1);
#pragma unroll
    for (int mi = 0; mi < 4; mi++) {
        acc[mi][0] = __builtin_amdgcn_mfma_f32_32x32x16_f16(wa, A[mi], acc[mi][0], 0, 0, 0);
        acc[mi][1] = __builtin_amdgcn_mfma_f32_32x32x16_f16(wb, A[mi], acc[mi][1], 0, 0, 0);
    }
    __builtin_amdgcn_s_setprio(0);
}

// ---------------------------------------------------------------------------
// One fused layer: C(128x256) = relu(A(128xK) @ W + b), in-place LDS->LDS.
// A ping-pong (1 kstep ahead) + 4-slot W ring (4 ksteps ahead). Per group:
// {prefA(g+1), W-reload} || sched_barrier(0) || 8 MFMA on resident regs.
// ---------------------------------------------------------------------------
template <int KT, int AMODE, int KS0>
__device__ __forceinline__ void layerT(const _Float16* abuf,
                                       const _Float16* __restrict__ xbuf,
                                       const half8* __restrict__ wq,
                                       const float* __restrict__ bias,
                                       _Float16* obuf,
                                       int lane, int wave) {
    constexpr int KTAIL = (KT % 4 == 0) ? 4 : (KT % 4);
    constexpr int KMAIN = KT - KTAIL;
    static_assert(KTAIL == 4 || KTAIL == 3, "tail must be 3 or 4 ksteps");
    static_assert(AMODE != 1 || KS0 == KMAIN, "L5 x-switch must align with tail");

    const int l31 = lane & 31, lhi = lane >> 5;
    const _Float16* aBase = abuf + lhi * 1024 + l31 * 8;
    const _Float16* xBase = xbuf + lhi * 1024 + l31 * 8;
    // W frag (kstep ks, n-tile wave*2+ni): wl[ks*512 + ni*64]
    const half8* wl = wq + (wave * 2) * 64 + lane;
    // Clamped W load (clamp only matters for KT=19's last ring slot).
    auto ldW = [&](int s, half8& wa, half8& wb) {
        int sc = s < KT ? s : KT - 1;
        wa = wl[sc * 512];
        wb = wl[sc * 512 + 64];
    };

    // Bias -> acc init: acc element g*4+r is channel wave*64 + ni*32 + lhi*4 + g*8 + r.
    floatx16 acc[4][2];
#pragma unroll
    for (int ni = 0; ni < 2; ni++) {
        floatx16 t;
#pragma unroll
        for (int g = 0; g < 4; g++) {
            floatx4 b = *(const floatx4*)(bias + wave * 64 + ni * 32 + g * 8 + lhi * 4);
#pragma unroll
            for (int r = 0; r < 4; r++) t[g * 4 + r] = b[r];
        }
#pragma unroll
        for (int mi = 0; mi < 4; mi++) acc[mi][ni] = t;
    }

    half8 A0[4], A1[4];
    half8 w0a, w0b, w1a, w1b, w2a, w2b, w3a, w3b;

    // Prologue: A(0) + W(0..3).
    prefA<AMODE, KS0>(A0, aBase, xBase, 0);
    ldW(0, w0a, w0b);
    ldW(1, w1a, w1b);
    ldW(2, w2a, w2b);
    ldW(3, w3a, w3b);

#pragma unroll 1
    for (int ks = 0; ks < KMAIN; ks += 4) {
        prefA<AMODE, KS0>(A1, aBase, xBase, ks + 1);
        __builtin_amdgcn_sched_barrier(0);
        mfma8(A0, w0a, w0b, acc);
        ldW(ks + 4, w0a, w0b);
        prefA<AMODE, KS0>(A0, aBase, xBase, ks + 2);
        __builtin_amdgcn_sched_barrier(0);
        mfma8(A1, w1a, w1b, acc);
        ldW(ks + 5, w1a, w1b);
        prefA<AMODE, KS0>(A1, aBase, xBase, ks + 3);
        __builtin_amdgcn_sched_barrier(0);
        mfma8(A0, w2a, w2b, acc);
        ldW(ks + 6, w2a, w2b);
        prefA<AMODE, KS0>(A0, aBase, xBase, ks + 4);
        __builtin_amdgcn_sched_barrier(0);
        mfma8(A1, w3a, w3b, acc);
        ldW(ks + 7, w3a, w3b);
    }
    // Tail: A(KMAIN) resident in A0; w0..w3 = W(KMAIN..KMAIN+3) (clamped).
    if constexpr (KTAIL == 4) {
        prefA<AMODE, KS0>(A1, aBase, xBase, KMAIN + 1);
        __builtin_amdgcn_sched_barrier(0);
        mfma8(A0, w0a, w0b, acc);
        prefA<AMODE, KS0>(A0, aBase, xBase, KMAIN + 2);
        __builtin_amdgcn_sched_barrier(0);
        mfma8(A1, w1a, w1b, acc);
        prefA<AMODE, KS0>(A1, aBase, xBase, KMAIN + 3);
        __builtin_amdgcn_sched_barrier(0);
        mfma8(A0, w2a, w2b, acc);
        __builtin_amdgcn_sched_barrier(0);
        mfma8(A1, w3a, w3b, acc);
    } else {  // KTAIL == 3
        prefA<AMODE, KS0>(A1, aBase, xBase, KMAIN + 1);
        __builtin_amdgcn_sched_barrier(0);
        mfma8(A0, w0a, w0b, acc);
        prefA<AMODE, KS0>(A0, aBase, xBase, KMAIN + 2);
        __builtin_amdgcn_sched_barrier(0);
        mfma8(A1, w1a, w1b, acc);
        __builtin_amdgcn_sched_barrier(0);
        mfma8(A0, w2a, w2b, acc);
    }

    // relu + fp16 cvt into regs BEFORE the barrier (shrink serialized tail).
    half4v hv[4][2][4];
#pragma unroll
    for (int mi = 0; mi < 4; mi++)
#pragma unroll
        for (int ni = 0; ni < 2; ni++)
#pragma unroll
            for (int g = 0; g < 4; g++) {
                half4v h;
#pragma unroll
                for (int r = 0; r < 4; r++) {
                    float v = acc[mi][ni][g * 4 + r];
                    v = v > 0.f ? v : 0.f;
                    h[r] = (_Float16)v;
                }
                hv[mi][ni][g] = h;
            }

    // In-place safety barrier: all waves' act-reads complete before any write.
    if (AMODE != 2) __syncthreads();
    // col = wave*64 + ni*32 + g*8 + lhi*4 + r -> chunk = wave*8 + ni*4 + g,
    // inner = lhi*4 + r; row = mi*32 + l31.
#pragma unroll
    for (int mi = 0; mi < 4; mi++) {
        _Float16* ob = obuf + (mi * 32 + l31) * 8 + lhi * 4;
#pragma unroll
        for (int ni = 0; ni < 2; ni++)
#pragma unroll
            for (int g = 0; g < 4; g++)
                *(half4v*)(ob + (wave * 8 + ni * 4 + g) * 1024) = hv[mi][ni][g];
    }
}

// Layer 9 (swapped): 256 -> 4 (N padded to 32). Each of 4 waves takes one
// 32-row m-frag; dual accumulators break the serial MFMA chain. Fully
// unrolled (16 W loads + 16 ds_reads scheduled freely by the compiler).
__device__ __forceinline__ void layer9T(const _Float16* abuf,
                                        const half8* __restrict__ wq,
                                        const float* __restrict__ b9,
                                        float* __restrict__ out, long r0,
                                        int lane, int wave) {
    const int l31 = lane & 31, lhi = lane >> 5;
    const _Float16* aBase = abuf + lhi * 1024 + (wave * 32 + l31) * 8;
    floatx16 acc_e = {}, acc_o = {};
    const half8* wl = wq + lane;
#pragma unroll
    for (int ks = 0; ks < 16; ks += 2) {
        half8 we = wl[ks * 64], wo = wl[(ks + 1) * 64];
        half8 ae = *(const half8*)(aBase + ks * 2048);
        half8 ao = *(const half8*)(aBase + (ks + 1) * 2048);
        acc_e = __builtin_amdgcn_mfma_f32_32x32x16_f16(we, ae, acc_e, 0, 0, 0);
        acc_o = __builtin_amdgcn_mfma_f32_32x32x16_f16(wo, ao, acc_o, 0, 0, 0);
    }
    if (lhi == 0) {
        floatx4 b4 = *(const floatx4*)(b9);
        floatx4 o;
#pragma unroll
        for (int r = 0; r < 4; r++) o[r] = acc_e[r] + acc_o[r] + b4[r];
        *(floatx4*)(out + (r0 + wave * 32 + l31) * 4) = o;
    }
}

__global__ __launch_bounds__(256, 2) void mlp_fused(
    const float* __restrict__ x, const _Float16* __restrict__ wpk,
    const float* __restrict__ b1, const float* __restrict__ b2,
    const float* __restrict__ b3, const float* __restrict__ b4,
    const float* __restrict__ b5, const float* __restrict__ b6,
    const float* __restrict__ b7, const float* __restrict__ b8,
    const float* __restrict__ b9, float* __restrict__ out) {
    // act 128x256 fp16 (64 KiB, in-place) + x 128x48 (12 KiB) = 76 KiB;
    // 4-wave blocks; 2 blocks/CU = 8 waves/CU = 2 waves/SIMD (256-reg cap).
    __shared__ _Float16 lds[128 * 256 + 128 * 48];
    _Float16* buf = lds;
    _Float16* xbuf = lds + 128 * 256;
    const int tid = threadIdx.x;
    const int lane = tid & 63, wave = tid >> 6;
    const long r0 = (long)blockIdx.x * 128;

    // Stage x (chunk-major): zero pad cols (39..47), fill cols 0..38.
    for (int i = tid; i < 128 * 9; i += 256) {
        int row = i / 9, col = 39 + (i - row * 9);
        xbuf[cmaj(row, col)] = (_Float16)0.f;
    }
    for (int i = tid; i < 128 * 39; i += 256) {
        int row = i / 39, col = i - row * 39;
        xbuf[cmaj(row, col)] = (_Float16)x[r0 * 39 + i];  // contiguous 4992 floats
    }
    __syncthreads();

    const half8* wp = (const half8*)wpk;  // tile = 64 half8 (1 KB)
    const half8* w1q = wp + (size_t)0 * 64;
    const half8* w2q = wp + (size_t)32 * 64;
    const half8* w3q = wp + (size_t)160 * 64;
    const half8* w4q = wp + (size_t)288 * 64;
    const half8* w5q = wp + (size_t)416 * 64;
    const half8* w6q = wp + (size_t)576 * 64;
    const half8* w7q = wp + (size_t)704 * 64;
    const half8* w8q = wp + (size_t)832 * 64;
    const half8* w9q = wp + (size_t)960 * 64;

    layerT<3, 2, 0>(xbuf, xbuf, w1q, b1, buf, lane, wave);   // x -> buf (K=48)
    __syncthreads();
    layerT<16, 0, 0>(buf, xbuf, w2q, b2, buf, lane, wave);
    __syncthreads();
    layerT<16, 0, 0>(buf, xbuf, w3q, b3, buf, lane, wave);
    __syncthreads();
    layerT<16, 0, 0>(buf, xbuf, w4q, b4, buf, lane, wave);
    __syncthreads();
    layerT<19, 1, 16>(buf, xbuf, w5q, b5, buf, lane, wave);  // [h|x] skip, K=304
    __syncthreads();
    layerT<16, 0, 0>(buf, xbuf, w6q, b6, buf, lane, wave);
    __syncthreads();
    layerT<16, 0, 0>(buf, xbuf, w7q, b7, buf, lane, wave);
    __syncthreads();
    layerT<16, 0, 0>(buf, xbuf, w8q, b8, buf, lane, wave);
    __syncthreads();
    layer9T(buf, w9q, b9, out, r0, lane, wave);
}

extern "C" void kernel_launch(void* const* d_in, const int* in_sizes, int n_in,
                              void* d_out, int out_size, void* d_ws, size_t ws_size,
                              hipStream_t stream) {
    const float* x = (const float*)d_in[0];
    const float* w[9];
    const float* b[9];
    for (int i = 0; i < 9; i++) {
        w[i] = (const float*)d_in[1 + 2 * i];
        b[i] = (const float*)d_in[2 + 2 * i];
    }
    _Float16* wpk = (_Float16*)d_ws;  // 999424 B

    pack_w32<<<244, 256, 0, stream>>>(w[0], w[1], w[2], w[3], w[4], w[5], w[6], w[7], w[8], wpk);
    mlp_fused<<<262144 / 128, 256, 0, stream>>>(x, wpk, b[0], b[1], b[2], b[3], b[4],
                                                b[5], b[6], b[7], b[8], (float*)d_out);
}